// Round 14
// baseline (109.674 us; speedup 1.0000x reference)
//
#include <hip/hip_runtime.h>

#define S_DIM 64
#define B_DIM 128
#define D_DIM 10000
#define NV4   2500          // D_DIM / 4
#define BLOCK 512
#define RPB   8             // rows per block = one row per wave
#define NBLK  (B_DIM * (S_DIM / RPB))   // 1024 blocks
#define NROWS (S_DIM * B_DIM)
#define NWAVE (BLOCK / 64)
#define FULLIT 39           // 2500 = 39*64 + 4

typedef float floatx4 __attribute__((ext_vector_type(4)));  // clang-native vec4

// bf16 pack/unpack (RNE rounding; lo in bits[15:0], hi in bits[31:16])
static __device__ __forceinline__ unsigned bf16pack(float lo, float hi) {
    unsigned a = __builtin_bit_cast(unsigned, lo);
    unsigned b = __builtin_bit_cast(unsigned, hi);
    a = (a + 0x7fffu + ((a >> 16) & 1u)) >> 16;
    b = (b + 0x7fffu + ((b >> 16) & 1u)) & 0xffff0000u;
    return (a & 0xffffu) | b;
}
static __device__ __forceinline__ float bf16lo(unsigned u) {
    return __builtin_bit_cast(float, u << 16);
}
static __device__ __forceinline__ float bf16hi(unsigned u) {
    return __builtin_bit_cast(float, u & 0xffff0000u);
}

// R12/R13 structure (wave-per-row, bf16 LDS tables, 32 waves/CU, XCD swizzle
// so the 8 blocks sharing b land on one XCD -> theta/y L2-resident) + R14:
// (1) fused last-block final reduce (removes kernel-2 launch + its serial
//     tail; safe now because live state is 3 scalars — R4/R5 spilled because
//     they fused while holding 40-80 VGPR arrays);
// (2) nontemporal noise loads (noise is read exactly once; skip L2/L3
//     allocation to cut churn).
// Per row: S = sum T*e, Q = sum (T*e)^2, P = sum W*e, e = exp(noise);
// loss_row = Q/S^2 - 2P/S + Y2_b. Max-subtraction skipped (eta ~ N(0,sqrt2),
// dataset max ~8.5, exp safe in fp32; softmax shift-invariant).
__global__ __launch_bounds__(BLOCK, 8) void perturbed_loss_waverow(
    const float* __restrict__ theta,   // [B, D]
    const float* __restrict__ y,       // [B, D]
    const float* __restrict__ noise,   // [S, B, D]
    double* __restrict__ blockloss,    // [NBLK]
    float*  __restrict__ y2arr,        // [B_DIM]
    unsigned int* __restrict__ counter,// zeroed by hipMemsetAsync each call
    float* __restrict__ out)
{
    __shared__ uint4  TV[NV4];         // 40000 B: {T01,T23,W01,W23} bf16-packed
    __shared__ float  redY[NWAVE];
    __shared__ double wloss[NWAVE];
    __shared__ double dred[NWAVE];
    __shared__ int    is_last;

    const int blk  = blockIdx.x;           // [0, NBLK)
    const int b    = ((blk >> 6) << 3) + (blk & 7);  // [0,128); blk%8 fixed per b
    const int s0   = ((blk >> 3) & 7) * RPB;         // [0,64) step 8
    const int tid  = threadIdx.x;
    const int lane = tid & 63;
    const int wave = tid >> 6;

    const float4* th4 = reinterpret_cast<const float4*>(theta + (size_t)b * D_DIM);
    const float4* y4  = reinterpret_cast<const float4*>(y     + (size_t)b * D_DIM);

    // ---- Phase 1: T=rnd_bf16(exp(theta)), W=rnd_bf16(T*y) -> LDS; Y2 ----
    float y2 = 0.0f;
    for (int i = tid; i < NV4; i += BLOCK) {
        float4 t  = th4[i];
        float4 yy = y4[i];
        unsigned tp0 = bf16pack(__expf(t.x), __expf(t.y));
        unsigned tp1 = bf16pack(__expf(t.z), __expf(t.w));
        unsigned wp0 = bf16pack(bf16lo(tp0) * yy.x, bf16hi(tp0) * yy.y);
        unsigned wp1 = bf16pack(bf16lo(tp1) * yy.z, bf16hi(tp1) * yy.w);
        TV[i] = make_uint4(tp0, tp1, wp0, wp1);
        y2 = fmaf(yy.x, yy.x, y2); y2 = fmaf(yy.y, yy.y, y2);
        y2 = fmaf(yy.z, yy.z, y2); y2 = fmaf(yy.w, yy.w, y2);
    }
    #pragma unroll
    for (int o = 32; o > 0; o >>= 1) y2 += __shfl_down(y2, o, 64);
    if (lane == 0) redY[wave] = y2;
    __syncthreads();                   // LDS TV + redY ready
    if (tid == 0 && ((blk >> 3) & 7) == 0) {  // one writer per b
        float t = 0.0f;
        #pragma unroll
        for (int w = 0; w < NWAVE; ++w) t += redY[w];
        y2arr[b] = t;                  // ordered by the release fetch_add below
    }

    // ---- Phase 2 (per-wave, independent): stream one noise row ----
    const int row = (s0 + wave) * B_DIM + b;
    const floatx4* nz4 = reinterpret_cast<const floatx4*>(noise + (size_t)row * D_DIM);

    float s = 0.0f, q = 0.0f, p = 0.0f;
    int i = lane;
    #pragma unroll 4
    for (int it = 0; it < FULLIT; ++it, i += 64) {
        floatx4 n = __builtin_nontemporal_load(&nz4[i]);
        uint4  u = TV[i];
        float e0 = __expf(n.x), e1 = __expf(n.y);
        float e2 = __expf(n.z), e3 = __expf(n.w);
        float t0 = bf16lo(u.x) * e0, t1 = bf16hi(u.x) * e1;
        float t2 = bf16lo(u.y) * e2, t3 = bf16hi(u.y) * e3;
        s += (t0 + t1) + (t2 + t3);
        q = fmaf(t0, t0, q); q = fmaf(t1, t1, q);
        q = fmaf(t2, t2, q); q = fmaf(t3, t3, q);
        p = fmaf(bf16lo(u.z), e0, p); p = fmaf(bf16hi(u.z), e1, p);
        p = fmaf(bf16lo(u.w), e2, p); p = fmaf(bf16hi(u.w), e3, p);
    }
    if (lane < 4) {                    // tail: float4 elements 2496..2499
        const int j = FULLIT * 64 + lane;
        floatx4 n = __builtin_nontemporal_load(&nz4[j]);
        uint4  u = TV[j];
        float e0 = __expf(n.x), e1 = __expf(n.y);
        float e2 = __expf(n.z), e3 = __expf(n.w);
        float t0 = bf16lo(u.x) * e0, t1 = bf16hi(u.x) * e1;
        float t2 = bf16lo(u.y) * e2, t3 = bf16hi(u.y) * e3;
        s += (t0 + t1) + (t2 + t3);
        q = fmaf(t0, t0, q); q = fmaf(t1, t1, q);
        q = fmaf(t2, t2, q); q = fmaf(t3, t3, q);
        p = fmaf(bf16lo(u.z), e0, p); p = fmaf(bf16hi(u.z), e1, p);
        p = fmaf(bf16lo(u.w), e2, p); p = fmaf(bf16hi(u.w), e3, p);
    }
    #pragma unroll
    for (int o = 32; o > 0; o >>= 1) {
        s += __shfl_down(s, o, 64);
        q += __shfl_down(q, o, 64);
        p += __shfl_down(p, o, 64);
    }
    if (lane == 0) {                   // fold this row's loss terms (double)
        double invS = 1.0 / (double)s;
        wloss[wave] = ((double)q * invS - 2.0 * (double)p) * invS;
    }
    __syncthreads();

    // ---- Completion: last block does the deterministic final combine ----
    if (tid == 0) {
        double t = 0.0;
        #pragma unroll
        for (int w = 0; w < NWAVE; ++w) t += wloss[w];
        blockloss[blk] = t;            // ordered by the release fetch_add
        unsigned int old = __hip_atomic_fetch_add(counter, 1u, __ATOMIC_ACQ_REL,
                                                  __HIP_MEMORY_SCOPE_AGENT);
        is_last = (old == (unsigned int)(NBLK - 1)) ? 1 : 0;
    }
    __syncthreads();
    if (is_last) {
        double acc = 0.0;
        for (int i2 = tid; i2 < NBLK; i2 += BLOCK)   // fixed order per thread
            acc += __hip_atomic_load(&blockloss[i2], __ATOMIC_RELAXED,
                                     __HIP_MEMORY_SCOPE_AGENT);
        if (tid < B_DIM)
            acc += (double)S_DIM *
                   (double)__hip_atomic_load(&y2arr[tid], __ATOMIC_RELAXED,
                                             __HIP_MEMORY_SCOPE_AGENT);
        #pragma unroll
        for (int o = 32; o > 0; o >>= 1) acc += __shfl_down(acc, o, 64);
        if (lane == 0) dred[wave] = acc;
        __syncthreads();
        if (tid == 0) {
            double t = 0.0;
            #pragma unroll
            for (int w = 0; w < NWAVE; ++w) t += dred[w];
            out[0] = (float)(t / ((double)S_DIM * (double)B_DIM * (double)D_DIM));
        }
    }
}

extern "C" void kernel_launch(void* const* d_in, const int* in_sizes, int n_in,
                              void* d_out, int out_size, void* d_ws, size_t ws_size,
                              hipStream_t stream) {
    const float* theta = (const float*)d_in[0];
    const float* y     = (const float*)d_in[1];
    const float* noise = (const float*)d_in[2];
    float* out        = (float*)d_out;
    double* blockloss = (double*)d_ws;                                // 8 KB
    float*  y2arr     = (float*)((char*)d_ws + NBLK * sizeof(double));// 512 B
    unsigned int* counter =
        (unsigned int*)((char*)d_ws + NBLK * sizeof(double) + 512);   // 4 B

    (void)hipMemsetAsync(counter, 0, sizeof(unsigned int), stream);
    perturbed_loss_waverow<<<NBLK, BLOCK, 0, stream>>>(theta, y, noise,
                                                       blockloss, y2arr,
                                                       counter, out);
}

// Round 15
// 105.129 us; speedup vs baseline: 1.0432x; 1.0432x over previous
//
#include <hip/hip_runtime.h>

#define S_DIM 64
#define B_DIM 128
#define D_DIM 10000
#define NV4   2500          // D_DIM / 4
#define BLOCK 512
#define RPB   8             // rows per block = one row per wave
#define NBLK  (B_DIM * (S_DIM / RPB))   // 1024 blocks (power of 2 — wrap trick)
#define NROWS (S_DIM * B_DIM)
#define NWAVE (BLOCK / 64)
#define FULLIT 39           // 2500 = 39*64 + 4

// bf16 pack/unpack (RNE rounding; lo in bits[15:0], hi in bits[31:16])
static __device__ __forceinline__ unsigned bf16pack(float lo, float hi) {
    unsigned a = __builtin_bit_cast(unsigned, lo);
    unsigned b = __builtin_bit_cast(unsigned, hi);
    a = (a + 0x7fffu + ((a >> 16) & 1u)) >> 16;
    b = (b + 0x7fffu + ((b >> 16) & 1u)) & 0xffff0000u;
    return (a & 0xffffu) | b;
}
static __device__ __forceinline__ float bf16lo(unsigned u) {
    return __builtin_bit_cast(float, u << 16);
}
static __device__ __forceinline__ float bf16hi(unsigned u) {
    return __builtin_bit_cast(float, u & 0xffff0000u);
}

// R13 memory path (wave-per-row, bf16 LDS tables, 32 waves/CU, XCD swizzle,
// PLAIN cached noise loads — R14 proved nontemporal kills the L3 reuse that
// serves ~half the noise stream: FETCH_SIZE 168 MB vs 327 MB, +42us) +
// fused last-block final reduce with a WRAP-MASK counter: NBLK=1024 divides
// 2^32, so ((fetch_add & (NBLK-1)) == NBLK-1) fires exactly once per launch
// regardless of the counter's initial value (poison-safe) -> no memset node,
// no kernel-2 launch gap. ACQ_REL RMW chain orders all blockloss stores
// before the last block's reads.
// Per row: S = sum T*e, Q = sum (T*e)^2, P = sum W*e, e = exp(noise);
// loss_row = Q/S^2 - 2P/S + Y2_b. Max-subtraction skipped (eta ~ N(0,sqrt2),
// dataset max ~8.5, exp safe in fp32; softmax shift-invariant).
__global__ __launch_bounds__(BLOCK, 8) void perturbed_loss_waverow(
    const float* __restrict__ theta,   // [B, D]
    const float* __restrict__ y,       // [B, D]
    const float* __restrict__ noise,   // [S, B, D]
    double* __restrict__ blockloss,    // [NBLK]
    float*  __restrict__ y2arr,        // [B_DIM]
    unsigned int* __restrict__ counter,// persistent; wrap-mask, never reset
    float* __restrict__ out)
{
    __shared__ uint4  TV[NV4];         // 40000 B: {T01,T23,W01,W23} bf16-packed
    __shared__ float  redY[NWAVE];
    __shared__ double wloss[NWAVE];
    __shared__ double dred[NWAVE];
    __shared__ int    is_last;

    const int blk  = blockIdx.x;           // [0, NBLK)
    const int b    = ((blk >> 6) << 3) + (blk & 7);  // [0,128); blk%8 fixed per b
    const int s0   = ((blk >> 3) & 7) * RPB;         // [0,64) step 8
    const int tid  = threadIdx.x;
    const int lane = tid & 63;
    const int wave = tid >> 6;

    const float4* th4 = reinterpret_cast<const float4*>(theta + (size_t)b * D_DIM);
    const float4* y4  = reinterpret_cast<const float4*>(y     + (size_t)b * D_DIM);

    // ---- Phase 1: T=rnd_bf16(exp(theta)), W=rnd_bf16(T*y) -> LDS; Y2 ----
    float y2 = 0.0f;
    for (int i = tid; i < NV4; i += BLOCK) {
        float4 t  = th4[i];
        float4 yy = y4[i];
        unsigned tp0 = bf16pack(__expf(t.x), __expf(t.y));
        unsigned tp1 = bf16pack(__expf(t.z), __expf(t.w));
        unsigned wp0 = bf16pack(bf16lo(tp0) * yy.x, bf16hi(tp0) * yy.y);
        unsigned wp1 = bf16pack(bf16lo(tp1) * yy.z, bf16hi(tp1) * yy.w);
        TV[i] = make_uint4(tp0, tp1, wp0, wp1);
        y2 = fmaf(yy.x, yy.x, y2); y2 = fmaf(yy.y, yy.y, y2);
        y2 = fmaf(yy.z, yy.z, y2); y2 = fmaf(yy.w, yy.w, y2);
    }
    #pragma unroll
    for (int o = 32; o > 0; o >>= 1) y2 += __shfl_down(y2, o, 64);
    if (lane == 0) redY[wave] = y2;
    __syncthreads();                   // LDS TV + redY ready
    if (tid == 0 && ((blk >> 3) & 7) == 0) {  // one writer per b
        float t = 0.0f;
        #pragma unroll
        for (int w = 0; w < NWAVE; ++w) t += redY[w];
        y2arr[b] = t;                  // ordered by the release fetch_add below
    }

    // ---- Phase 2 (per-wave, independent): stream one noise row ----
    const int row = (s0 + wave) * B_DIM + b;
    const float4* nz4 = reinterpret_cast<const float4*>(noise + (size_t)row * D_DIM);

    float s = 0.0f, q = 0.0f, p = 0.0f;
    int i = lane;
    #pragma unroll 4
    for (int it = 0; it < FULLIT; ++it, i += 64) {
        float4 n = nz4[i];
        uint4  u = TV[i];
        float e0 = __expf(n.x), e1 = __expf(n.y);
        float e2 = __expf(n.z), e3 = __expf(n.w);
        float t0 = bf16lo(u.x) * e0, t1 = bf16hi(u.x) * e1;
        float t2 = bf16lo(u.y) * e2, t3 = bf16hi(u.y) * e3;
        s += (t0 + t1) + (t2 + t3);
        q = fmaf(t0, t0, q); q = fmaf(t1, t1, q);
        q = fmaf(t2, t2, q); q = fmaf(t3, t3, q);
        p = fmaf(bf16lo(u.z), e0, p); p = fmaf(bf16hi(u.z), e1, p);
        p = fmaf(bf16lo(u.w), e2, p); p = fmaf(bf16hi(u.w), e3, p);
    }
    if (lane < 4) {                    // tail: float4 elements 2496..2499
        const int j = FULLIT * 64 + lane;
        float4 n = nz4[j];
        uint4  u = TV[j];
        float e0 = __expf(n.x), e1 = __expf(n.y);
        float e2 = __expf(n.z), e3 = __expf(n.w);
        float t0 = bf16lo(u.x) * e0, t1 = bf16hi(u.x) * e1;
        float t2 = bf16lo(u.y) * e2, t3 = bf16hi(u.y) * e3;
        s += (t0 + t1) + (t2 + t3);
        q = fmaf(t0, t0, q); q = fmaf(t1, t1, q);
        q = fmaf(t2, t2, q); q = fmaf(t3, t3, q);
        p = fmaf(bf16lo(u.z), e0, p); p = fmaf(bf16hi(u.z), e1, p);
        p = fmaf(bf16lo(u.w), e2, p); p = fmaf(bf16hi(u.w), e3, p);
    }
    #pragma unroll
    for (int o = 32; o > 0; o >>= 1) {
        s += __shfl_down(s, o, 64);
        q += __shfl_down(q, o, 64);
        p += __shfl_down(p, o, 64);
    }
    if (lane == 0) {                   // fold this row's loss terms (double)
        double invS = 1.0 / (double)s;
        wloss[wave] = ((double)q * invS - 2.0 * (double)p) * invS;
    }
    __syncthreads();

    // ---- Completion: wrap-mask counter; last block does final combine ----
    if (tid == 0) {
        double t = 0.0;
        #pragma unroll
        for (int w = 0; w < NWAVE; ++w) t += wloss[w];
        blockloss[blk] = t;            // ordered by the release fetch_add
        unsigned int old = __hip_atomic_fetch_add(counter, 1u, __ATOMIC_ACQ_REL,
                                                  __HIP_MEMORY_SCOPE_AGENT);
        is_last = ((old & (unsigned int)(NBLK - 1)) == (unsigned int)(NBLK - 1));
    }
    __syncthreads();
    if (is_last) {
        double acc = 0.0;
        for (int i2 = tid; i2 < NBLK; i2 += BLOCK)   // fixed order per thread
            acc += __hip_atomic_load(&blockloss[i2], __ATOMIC_RELAXED,
                                     __HIP_MEMORY_SCOPE_AGENT);
        if (tid < B_DIM)
            acc += (double)S_DIM *
                   (double)__hip_atomic_load(&y2arr[tid], __ATOMIC_RELAXED,
                                             __HIP_MEMORY_SCOPE_AGENT);
        #pragma unroll
        for (int o = 32; o > 0; o >>= 1) acc += __shfl_down(acc, o, 64);
        if (lane == 0) dred[wave] = acc;
        __syncthreads();
        if (tid == 0) {
            double t = 0.0;
            #pragma unroll
            for (int w = 0; w < NWAVE; ++w) t += dred[w];
            out[0] = (float)(t / ((double)S_DIM * (double)B_DIM * (double)D_DIM));
        }
    }
}

extern "C" void kernel_launch(void* const* d_in, const int* in_sizes, int n_in,
                              void* d_out, int out_size, void* d_ws, size_t ws_size,
                              hipStream_t stream) {
    const float* theta = (const float*)d_in[0];
    const float* y     = (const float*)d_in[1];
    const float* noise = (const float*)d_in[2];
    float* out        = (float*)d_out;
    double* blockloss = (double*)d_ws;                                // 8 KB
    float*  y2arr     = (float*)((char*)d_ws + NBLK * sizeof(double));// 512 B
    unsigned int* counter =
        (unsigned int*)((char*)d_ws + NBLK * sizeof(double) + 512);   // 4 B

    perturbed_loss_waverow<<<NBLK, BLOCK, 0, stream>>>(theta, y, noise,
                                                       blockloss, y2arr,
                                                       counter, out);
}

// Round 16
// 101.891 us; speedup vs baseline: 1.0764x; 1.0318x over previous
//
#include <hip/hip_runtime.h>

#define S_DIM 64
#define B_DIM 128
#define D_DIM 10000
#define NV4   2500          // D_DIM / 4
#define BLOCK 512
#define RPB   8             // rows per block = one row per wave
#define NBLK  (B_DIM * (S_DIM / RPB))   // 1024 blocks (power of 2 — wrap trick)
#define NROWS (S_DIM * B_DIM)
#define NWAVE (BLOCK / 64)
#define FULLIT 39           // 2500 = 39*64 + 4

// bf16 pack/unpack (RNE rounding; lo in bits[15:0], hi in bits[31:16])
static __device__ __forceinline__ unsigned bf16pack(float lo, float hi) {
    unsigned a = __builtin_bit_cast(unsigned, lo);
    unsigned b = __builtin_bit_cast(unsigned, hi);
    a = (a + 0x7fffu + ((a >> 16) & 1u)) >> 16;
    b = (b + 0x7fffu + ((b >> 16) & 1u)) & 0xffff0000u;
    return (a & 0xffffu) | b;
}
static __device__ __forceinline__ float bf16lo(unsigned u) {
    return __builtin_bit_cast(float, u << 16);
}
static __device__ __forceinline__ float bf16hi(unsigned u) {
    return __builtin_bit_cast(float, u & 0xffff0000u);
}

// R13 memory path unchanged (wave-per-row, bf16 LDS tables, 32 waves/CU,
// XCD swizzle, PLAIN cached noise loads, unroll 4). Fused tail, take 2:
// R15 proved per-block ACQ_REL costs ~37us — the acquire half invalidates
// the XCD's L2 at every block end (128x per XCD), destroying theta/y
// residency. Fix: per-block RMW is RELEASE-only (writeback of ~8B dirty,
// no invalidate); ONLY the last block (wrap-mask counter: NBLK=1024 divides
// 2^32, so (old & (NBLK-1))==NBLK-1 fires exactly once per launch from any
// initial/poisoned counter value) does a single ACQUIRE load before reading
// partials — one L2 invalidate per launch, also needed for cross-replay
// freshness of blockloss/y2arr lines.
// Per row: S = sum T*e, Q = sum (T*e)^2, P = sum W*e, e = exp(noise);
// loss_row = Q/S^2 - 2P/S + Y2_b. Max-subtraction skipped (eta ~ N(0,sqrt2),
// dataset max ~8.5, exp safe in fp32; softmax shift-invariant).
__global__ __launch_bounds__(BLOCK, 8) void perturbed_loss_waverow(
    const float* __restrict__ theta,   // [B, D]
    const float* __restrict__ y,       // [B, D]
    const float* __restrict__ noise,   // [S, B, D]
    double* __restrict__ blockloss,    // [NBLK]
    float*  __restrict__ y2arr,        // [B_DIM]
    unsigned int* __restrict__ counter,// persistent; wrap-mask, never reset
    float* __restrict__ out)
{
    __shared__ uint4  TV[NV4];         // 40000 B: {T01,T23,W01,W23} bf16-packed
    __shared__ float  redY[NWAVE];
    __shared__ double wloss[NWAVE];
    __shared__ double dred[NWAVE];
    __shared__ int    is_last;

    const int blk  = blockIdx.x;           // [0, NBLK)
    const int b    = ((blk >> 6) << 3) + (blk & 7);  // [0,128); blk%8 fixed per b
    const int s0   = ((blk >> 3) & 7) * RPB;         // [0,64) step 8
    const int tid  = threadIdx.x;
    const int lane = tid & 63;
    const int wave = tid >> 6;

    const float4* th4 = reinterpret_cast<const float4*>(theta + (size_t)b * D_DIM);
    const float4* y4  = reinterpret_cast<const float4*>(y     + (size_t)b * D_DIM);

    // ---- Phase 1: T=rnd_bf16(exp(theta)), W=rnd_bf16(T*y) -> LDS; Y2 ----
    float y2 = 0.0f;
    for (int i = tid; i < NV4; i += BLOCK) {
        float4 t  = th4[i];
        float4 yy = y4[i];
        unsigned tp0 = bf16pack(__expf(t.x), __expf(t.y));
        unsigned tp1 = bf16pack(__expf(t.z), __expf(t.w));
        unsigned wp0 = bf16pack(bf16lo(tp0) * yy.x, bf16hi(tp0) * yy.y);
        unsigned wp1 = bf16pack(bf16lo(tp1) * yy.z, bf16hi(tp1) * yy.w);
        TV[i] = make_uint4(tp0, tp1, wp0, wp1);
        y2 = fmaf(yy.x, yy.x, y2); y2 = fmaf(yy.y, yy.y, y2);
        y2 = fmaf(yy.z, yy.z, y2); y2 = fmaf(yy.w, yy.w, y2);
    }
    #pragma unroll
    for (int o = 32; o > 0; o >>= 1) y2 += __shfl_down(y2, o, 64);
    if (lane == 0) redY[wave] = y2;
    __syncthreads();                   // LDS TV + redY ready
    if (tid == 0 && ((blk >> 3) & 7) == 0) {  // one writer per b
        float t = 0.0f;
        #pragma unroll
        for (int w = 0; w < NWAVE; ++w) t += redY[w];
        y2arr[b] = t;                  // ordered by this thread's release RMW
    }

    // ---- Phase 2 (per-wave, independent): stream one noise row ----
    const int row = (s0 + wave) * B_DIM + b;
    const float4* nz4 = reinterpret_cast<const float4*>(noise + (size_t)row * D_DIM);

    float s = 0.0f, q = 0.0f, p = 0.0f;
    int i = lane;
    #pragma unroll 4
    for (int it = 0; it < FULLIT; ++it, i += 64) {
        float4 n = nz4[i];
        uint4  u = TV[i];
        float e0 = __expf(n.x), e1 = __expf(n.y);
        float e2 = __expf(n.z), e3 = __expf(n.w);
        float t0 = bf16lo(u.x) * e0, t1 = bf16hi(u.x) * e1;
        float t2 = bf16lo(u.y) * e2, t3 = bf16hi(u.y) * e3;
        s += (t0 + t1) + (t2 + t3);
        q = fmaf(t0, t0, q); q = fmaf(t1, t1, q);
        q = fmaf(t2, t2, q); q = fmaf(t3, t3, q);
        p = fmaf(bf16lo(u.z), e0, p); p = fmaf(bf16hi(u.z), e1, p);
        p = fmaf(bf16lo(u.w), e2, p); p = fmaf(bf16hi(u.w), e3, p);
    }
    if (lane < 4) {                    // tail: float4 elements 2496..2499
        const int j = FULLIT * 64 + lane;
        float4 n = nz4[j];
        uint4  u = TV[j];
        float e0 = __expf(n.x), e1 = __expf(n.y);
        float e2 = __expf(n.z), e3 = __expf(n.w);
        float t0 = bf16lo(u.x) * e0, t1 = bf16hi(u.x) * e1;
        float t2 = bf16lo(u.y) * e2, t3 = bf16hi(u.y) * e3;
        s += (t0 + t1) + (t2 + t3);
        q = fmaf(t0, t0, q); q = fmaf(t1, t1, q);
        q = fmaf(t2, t2, q); q = fmaf(t3, t3, q);
        p = fmaf(bf16lo(u.z), e0, p); p = fmaf(bf16hi(u.z), e1, p);
        p = fmaf(bf16lo(u.w), e2, p); p = fmaf(bf16hi(u.w), e3, p);
    }
    #pragma unroll
    for (int o = 32; o > 0; o >>= 1) {
        s += __shfl_down(s, o, 64);
        q += __shfl_down(q, o, 64);
        p += __shfl_down(p, o, 64);
    }
    if (lane == 0) {                   // fold this row's loss terms (double)
        double invS = 1.0 / (double)s;
        wloss[wave] = ((double)q * invS - 2.0 * (double)p) * invS;
    }
    __syncthreads();

    // ---- Completion: RELEASE-only per block; last block ACQUIREs once ----
    if (tid == 0) {
        double t = 0.0;
        #pragma unroll
        for (int w = 0; w < NWAVE; ++w) t += wloss[w];
        blockloss[blk] = t;            // made visible by the release RMW below
        unsigned int old = __hip_atomic_fetch_add(counter, 1u, __ATOMIC_RELEASE,
                                                  __HIP_MEMORY_SCOPE_AGENT);
        is_last = ((old & (unsigned int)(NBLK - 1)) == (unsigned int)(NBLK - 1));
    }
    __syncthreads();
    if (is_last) {
        if (tid == 0) {                // single acquire: syncs with all 1024
            (void)__hip_atomic_load(counter, __ATOMIC_ACQUIRE,
                                    __HIP_MEMORY_SCOPE_AGENT);
        }
        __syncthreads();               // invalidate done before any read below
        double acc = 0.0;
        for (int i2 = tid; i2 < NBLK; i2 += BLOCK)   // fixed order per thread
            acc += __hip_atomic_load(&blockloss[i2], __ATOMIC_RELAXED,
                                     __HIP_MEMORY_SCOPE_AGENT);
        if (tid < B_DIM)
            acc += (double)S_DIM *
                   (double)__hip_atomic_load(&y2arr[tid], __ATOMIC_RELAXED,
                                             __HIP_MEMORY_SCOPE_AGENT);
        #pragma unroll
        for (int o = 32; o > 0; o >>= 1) acc += __shfl_down(acc, o, 64);
        if (lane == 0) dred[wave] = acc;
        __syncthreads();
        if (tid == 0) {
            double t = 0.0;
            #pragma unroll
            for (int w = 0; w < NWAVE; ++w) t += dred[w];
            out[0] = (float)(t / ((double)S_DIM * (double)B_DIM * (double)D_DIM));
        }
    }
}

extern "C" void kernel_launch(void* const* d_in, const int* in_sizes, int n_in,
                              void* d_out, int out_size, void* d_ws, size_t ws_size,
                              hipStream_t stream) {
    const float* theta = (const float*)d_in[0];
    const float* y     = (const float*)d_in[1];
    const float* noise = (const float*)d_in[2];
    float* out        = (float*)d_out;
    double* blockloss = (double*)d_ws;                                // 8 KB
    float*  y2arr     = (float*)((char*)d_ws + NBLK * sizeof(double));// 512 B
    unsigned int* counter =
        (unsigned int*)((char*)d_ws + NBLK * sizeof(double) + 512);   // 4 B

    perturbed_loss_waverow<<<NBLK, BLOCK, 0, stream>>>(theta, y, noise,
                                                       blockloss, y2arr,
                                                       counter, out);
}

// Round 17
// 65.508 us; speedup vs baseline: 1.6742x; 1.5554x over previous
//
#include <hip/hip_runtime.h>

#define S_DIM 64
#define B_DIM 128
#define D_DIM 10000
#define NV4   2500          // D_DIM / 4
#define BLOCK 1024
#define RPB   16            // rows per block = one row per wave (16 waves)
#define NBLK  (B_DIM * (S_DIM / RPB))   // 512 blocks
#define NROWS (S_DIM * B_DIM)
#define NWAVE (BLOCK / 64)  // 16
#define FULLIT 39           // 2500 = 39*64 + 4

// bf16 pack/unpack (RNE rounding; lo in bits[15:0], hi in bits[31:16])
static __device__ __forceinline__ unsigned bf16pack(float lo, float hi) {
    unsigned a = __builtin_bit_cast(unsigned, lo);
    unsigned b = __builtin_bit_cast(unsigned, hi);
    a = (a + 0x7fffu + ((a >> 16) & 1u)) >> 16;
    b = (b + 0x7fffu + ((b >> 16) & 1u)) & 0xffff0000u;
    return (a & 0xffffu) | b;
}
static __device__ __forceinline__ float bf16lo(unsigned u) {
    return __builtin_bit_cast(float, u << 16);
}
static __device__ __forceinline__ float bf16hi(unsigned u) {
    return __builtin_bit_cast(float, u & 0xffff0000u);
}

// R13 memory path (wave-per-row, bf16 LDS tables, XCD swizzle, plain cached
// noise loads, unroll 4, TWO-kernel structure — R14/15/16 proved any fused
// tail costs ~35us regardless of atomic ordering; fusion abandoned).
// R17: BLOCK 512->1024, RPB 8->16, NBLK->512. Thread limit (2048/CU) gives
// 2 blocks/CU = still 32 waves/CU (max), but each CU builds only 2 exp-tables
// per pass instead of 4, each with 1024 threads -> phase-1 serial cost per CU
// ~6us -> ~2us. Same 40KB LDS, same 64-VGPR cap (1024 thr x 8 waves/EU =>
// 2 blocks/CU), phase-2 body byte-identical.
// XCD swizzle: blk bits [8:5]=b>>3, [4:3]=sgroup, [2:0]=b&7 — bijective, and
// the 4 blocks sharing b keep blk%8 constant -> one XCD owns each b
// (16 b's = 1.28 MB theta/y per XCD L2).
// Per row: S = sum T*e, Q = sum (T*e)^2, P = sum W*e, e = exp(noise);
// loss_row = Q/S^2 - 2P/S + Y2_b. Max-subtraction skipped (eta ~ N(0,sqrt2),
// dataset max ~8.5, exp safe in fp32; softmax shift-invariant).
__global__ __launch_bounds__(BLOCK, 8) void perturbed_loss_waverow(
    const float* __restrict__ theta,   // [B, D]
    const float* __restrict__ y,       // [B, D]
    const float* __restrict__ noise,   // [S, B, D]
    double* __restrict__ blockloss,    // [NBLK]
    float*  __restrict__ y2arr)        // [B_DIM]
{
    __shared__ uint4  TV[NV4];         // 40000 B: {T01,T23,W01,W23} bf16-packed
    __shared__ float  redY[NWAVE];
    __shared__ double wloss[NWAVE];

    const int blk  = blockIdx.x;                     // [0, NBLK)
    const int b    = ((blk >> 5) << 3) + (blk & 7);  // [0,128); blk%8 fixed per b
    const int s0   = ((blk >> 3) & 3) * RPB;         // {0,16,32,48}
    const int tid  = threadIdx.x;
    const int lane = tid & 63;
    const int wave = tid >> 6;

    const float4* th4 = reinterpret_cast<const float4*>(theta + (size_t)b * D_DIM);
    const float4* y4  = reinterpret_cast<const float4*>(y     + (size_t)b * D_DIM);

    // ---- Phase 1: T=rnd_bf16(exp(theta)), W=rnd_bf16(T*y) -> LDS; Y2 ----
    float y2 = 0.0f;
    for (int i = tid; i < NV4; i += BLOCK) {
        float4 t  = th4[i];
        float4 yy = y4[i];
        unsigned tp0 = bf16pack(__expf(t.x), __expf(t.y));
        unsigned tp1 = bf16pack(__expf(t.z), __expf(t.w));
        unsigned wp0 = bf16pack(bf16lo(tp0) * yy.x, bf16hi(tp0) * yy.y);
        unsigned wp1 = bf16pack(bf16lo(tp1) * yy.z, bf16hi(tp1) * yy.w);
        TV[i] = make_uint4(tp0, tp1, wp0, wp1);
        y2 = fmaf(yy.x, yy.x, y2); y2 = fmaf(yy.y, yy.y, y2);
        y2 = fmaf(yy.z, yy.z, y2); y2 = fmaf(yy.w, yy.w, y2);
    }
    #pragma unroll
    for (int o = 32; o > 0; o >>= 1) y2 += __shfl_down(y2, o, 64);
    if (lane == 0) redY[wave] = y2;
    __syncthreads();                   // LDS TV + redY ready
    if (tid == 0 && ((blk >> 3) & 3) == 0) {  // one writer per b
        float t = 0.0f;
        #pragma unroll
        for (int w = 0; w < NWAVE; ++w) t += redY[w];
        y2arr[b] = t;
    }

    // ---- Phase 2 (per-wave, independent): stream one noise row ----
    const int row = (s0 + wave) * B_DIM + b;
    const float4* nz4 = reinterpret_cast<const float4*>(noise + (size_t)row * D_DIM);

    float s = 0.0f, q = 0.0f, p = 0.0f;
    int i = lane;
    #pragma unroll 4
    for (int it = 0; it < FULLIT; ++it, i += 64) {
        float4 n = nz4[i];
        uint4  u = TV[i];
        float e0 = __expf(n.x), e1 = __expf(n.y);
        float e2 = __expf(n.z), e3 = __expf(n.w);
        float t0 = bf16lo(u.x) * e0, t1 = bf16hi(u.x) * e1;
        float t2 = bf16lo(u.y) * e2, t3 = bf16hi(u.y) * e3;
        s += (t0 + t1) + (t2 + t3);
        q = fmaf(t0, t0, q); q = fmaf(t1, t1, q);
        q = fmaf(t2, t2, q); q = fmaf(t3, t3, q);
        p = fmaf(bf16lo(u.z), e0, p); p = fmaf(bf16hi(u.z), e1, p);
        p = fmaf(bf16lo(u.w), e2, p); p = fmaf(bf16hi(u.w), e3, p);
    }
    if (lane < 4) {                    // tail: float4 elements 2496..2499
        const int j = FULLIT * 64 + lane;
        float4 n = nz4[j];
        uint4  u = TV[j];
        float e0 = __expf(n.x), e1 = __expf(n.y);
        float e2 = __expf(n.z), e3 = __expf(n.w);
        float t0 = bf16lo(u.x) * e0, t1 = bf16hi(u.x) * e1;
        float t2 = bf16lo(u.y) * e2, t3 = bf16hi(u.y) * e3;
        s += (t0 + t1) + (t2 + t3);
        q = fmaf(t0, t0, q); q = fmaf(t1, t1, q);
        q = fmaf(t2, t2, q); q = fmaf(t3, t3, q);
        p = fmaf(bf16lo(u.z), e0, p); p = fmaf(bf16hi(u.z), e1, p);
        p = fmaf(bf16lo(u.w), e2, p); p = fmaf(bf16hi(u.w), e3, p);
    }
    #pragma unroll
    for (int o = 32; o > 0; o >>= 1) {
        s += __shfl_down(s, o, 64);
        q += __shfl_down(q, o, 64);
        p += __shfl_down(p, o, 64);
    }
    if (lane == 0) {                   // fold this row's loss terms (double)
        double invS = 1.0 / (double)s;
        wloss[wave] = ((double)q * invS - 2.0 * (double)p) * invS;
    }
    __syncthreads();
    if (tid == 0) {
        double t = 0.0;
        #pragma unroll
        for (int w = 0; w < NWAVE; ++w) t += wloss[w];
        blockloss[blk] = t;
    }
}

// Deterministic fixed-order final combine (512 doubles + 128 y2 floats).
__global__ __launch_bounds__(256) void reduce_final(
    const double* __restrict__ blockloss,
    const float*  __restrict__ y2arr,
    float* __restrict__ out)
{
    __shared__ double red[4];
    const int tid  = threadIdx.x;
    const int lane = tid & 63;
    const int wave = tid >> 6;

    double acc = 0.0;
    for (int i = tid; i < NBLK; i += 256) acc += blockloss[i];
    if (tid < B_DIM) acc += (double)S_DIM * (double)y2arr[tid];
    #pragma unroll
    for (int o = 32; o > 0; o >>= 1) acc += __shfl_down(acc, o, 64);
    if (lane == 0) red[wave] = acc;
    __syncthreads();
    if (tid == 0) {
        double t = ((red[0] + red[1]) + (red[2] + red[3]));
        out[0] = (float)(t / ((double)S_DIM * (double)B_DIM * (double)D_DIM));
    }
}

extern "C" void kernel_launch(void* const* d_in, const int* in_sizes, int n_in,
                              void* d_out, int out_size, void* d_ws, size_t ws_size,
                              hipStream_t stream) {
    const float* theta = (const float*)d_in[0];
    const float* y     = (const float*)d_in[1];
    const float* noise = (const float*)d_in[2];
    float* out        = (float*)d_out;
    double* blockloss = (double*)d_ws;                                // 4 KB
    float*  y2arr     = (float*)((char*)d_ws + NBLK * sizeof(double));// 512 B

    perturbed_loss_waverow<<<NBLK, BLOCK, 0, stream>>>(theta, y, noise,
                                                       blockloss, y2arr);
    reduce_final<<<1, 256, 0, stream>>>(blockloss, y2arr, out);
}